// Round 6
// baseline (2855.078 us; speedup 1.0000x reference)
//
#include <hip/hip_runtime.h>

typedef unsigned short u16;
typedef __bf16 bf16x8 __attribute__((ext_vector_type(8)));
typedef float  f32x4  __attribute__((ext_vector_type(4)));

#define T_STEPS 128

// ---- ws element-offset layout (u16 elements unless noted) ----
// PK1  @      0 : 16 ftiles * 9 kt * 512 = 73728   (Wm0 -> bf16 A-frags)
// PK2  @  73728 : 48 * 9 * 512          = 221184   (Wf10|Wf20|Wh0)
// PK3  @ 294912 : 16 * 9 * 512          = 73728    (Wm1, rows permuted to ACT2 layout)
// BIAS @ 368640 : 1288 floats = 2576 u16 (B1[256] B2[768] B3[256] BS[8])
// HW   @ 371216 : 8 * 256 = 2048        (head weights [o][k], bf16)

__device__ __forceinline__ float bf2f(u16 h) {
  union { unsigned int u; float f; } v; v.u = ((unsigned int)h) << 16; return v.f;
}
__device__ __forceinline__ u16 f2bf(float f) {
  union { float f; unsigned int u; } v; v.f = f;
  unsigned int u = v.u;
  return (u16)((u + 0x7fffu + ((u >> 16) & 1u)) >> 16);
}
__device__ __forceinline__ unsigned int pack2(float a, float b) {
  return (unsigned int)f2bf(a) | ((unsigned int)f2bf(b) << 16);
}
__device__ __forceinline__ float clampf(float x, float lo, float hi) {
  return fmaxf(lo, fminf(x, hi));   // NaN-absorbing insurance; no-op for correct values
}
__device__ __forceinline__ float tanh_fast(float x) {
  float e = __expf(2.0f * x);
  return 1.0f - 2.0f * __builtin_amdgcn_rcpf(e + 1.0f);
}

// B-fragment-order LDS address of element (k,n): tile(k>>5)*512 + quad*128 + n*8 + (k&7)
// D-epilogue destination for (ft, q, nidx), writing 4 consecutive f = ft*16+q*4+r:
__device__ __forceinline__ int dstOff(int ft, int q, int nidx) {
  return ((ft >> 1) << 9) + (((((ft & 1) << 1) + (q >> 1))) << 7) + (nidx << 3) + ((q & 1) << 2);
}

// ---------------- weight repack: f32 -> bf16 MFMA A-fragments (runs every call) ----------------
__global__ void egbrnn_prep(
    const float* __restrict__ Wm0, const float* __restrict__ Wm1,
    const float* __restrict__ Wf10, const float* __restrict__ Wf11,
    const float* __restrict__ Wf20, const float* __restrict__ Wf21,
    const float* __restrict__ Wh0, const float* __restrict__ Wh1,
    const float* __restrict__ bm0, const float* __restrict__ bm1,
    const float* __restrict__ bf10, const float* __restrict__ bf11,
    const float* __restrict__ bf20, const float* __restrict__ bf21,
    const float* __restrict__ bh0, const float* __restrict__ bh1,
    u16* __restrict__ ws)
{
  int idx = blockIdx.x * 256 + threadIdx.x;
  // ---- PK1: Wm0, K rows: [c 0-255, sn 256-259], pad->288 ----
  if (idx < 73728) {
    int tile = idx >> 9, r = idx & 511;
    int lane = r >> 3, j = r & 7;
    int ft = tile / 9, kt = tile - ft * 9;
    int m = (ft << 4) + (lane & 15);
    int k = (kt << 5) + ((lane >> 4) << 3) + j;
    ws[idx] = (k < 260) ? f2bf(Wm0[k * 256 + m]) : (u16)0;
    return;
  }
  idx -= 73728;
  // ---- PK2: [Wf10 | Wf20 | Wh0], ACT2 K layout [cu 0-255, sn 256-259, meas/60 260-261, pad] ----
  if (idx < 221184) {
    int tile = idx >> 9, r = idx & 511;
    int lane = r >> 3, j = r & 7;
    int ft = tile / 9, kt = tile - ft * 9;
    int F = (ft << 4) + (lane & 15);
    int k = (kt << 5) + ((lane >> 4) << 3) + j;
    int sel = F >> 8, col = F & 255;
    u16 v = 0;
    if (sel == 0)      { if (k < 260) v = f2bf(Wf10[k * 256 + col]); }
    else if (sel == 1) { if (k < 260) v = f2bf(Wf20[k * 256 + col]); }
    else               { if (k < 262) v = f2bf(Wh0 [k * 256 + col]); }
    ws[73728 + idx] = v;
    return;
  }
  idx -= 221184;
  // ---- PK3: Wm1 rows permuted to ACT2 layout: k<256->cu; k 260,261->meas rows 256,257; k 264..267->supd rows 258..261 ----
  if (idx < 73728) {
    int tile = idx >> 9, r = idx & 511;
    int lane = r >> 3, j = r & 7;
    int ft = tile / 9, kt = tile - ft * 9;
    int m = (ft << 4) + (lane & 15);
    int k = (kt << 5) + ((lane >> 4) << 3) + j;
    int row = -1;
    if (k < 256) row = k;
    else if (k == 260 || k == 261) row = 256 + (k - 260);
    else if (k >= 264 && k < 268)  row = 258 + (k - 264);
    ws[294912 + idx] = (row >= 0) ? f2bf(Wm1[row * 256 + m]) : (u16)0;
    return;
  }
  idx -= 73728;
  // ---- biases (fp32) ----
  if (idx < 1288) {
    float* BIAS = (float*)(ws + 368640);
    float h;
    if (idx < 256) h = bm0[idx];
    else if (idx < 1024) {
      int f = idx - 256;
      h = (f < 256) ? bf10[f] : (f < 512 ? bf20[f - 256] : bh0[f - 512]);
    } else if (idx < 1280) h = bm1[idx - 1024];
    else {
      int i2 = idx - 1280;
      h = (i2 < 2) ? bf11[i2] : (i2 < 6 ? bf21[i2 - 2] : bh1[i2 - 6]);
    }
    BIAS[idx] = h;
    return;
  }
  idx -= 1288;
  // ---- head weights [o][k], bf16 ----
  if (idx < 2048) {
    int o = idx >> 8, k = idx & 255;
    float v;
    if (o < 2)      v = Wf11[k * 2 + o];
    else if (o < 6) v = Wf21[k * 4 + (o - 2)];
    else            v = Wh1[k * 2 + (o - 6)];
    ws[371216 + idx] = f2bf(v);
  }
}

// ---------------- main: 128 blocks x 1024 threads (16 waves), 16 batch rows per block ----------------
__global__ __launch_bounds__(1024, 1) void egbrnn_main(
    const float* __restrict__ x, const float* __restrict__ target,
    const float* __restrict__ c0, const u16* __restrict__ wsp,
    float* __restrict__ out)
{
  // Activations in exact MFMA B-fragment tile order (conflict-free wave-sequential reads).
  __shared__ __align__(16) u16 ACT1[9 * 512];   // k: 0-255 c, 256-259 sn, rest 0
  __shared__ __align__(16) u16 ACT2[9 * 512];   // k: 0-255 cu, 256-259 sn, 260-261 meas/60, 264-267 supd/60
  __shared__ __align__(16) u16 S2O[24 * 512];   // f: 0-255 t1, 256-511 t2, 512-767 th
  __shared__ __align__(16) u16 HWs[2048];       // head weights [o][k]
  __shared__ __align__(16) float SM[128];       // [b][o]: d0 d1 pv0..3 hv0 hv1

  const u16* PK1 = wsp;
  const u16* PK2 = wsp + 73728;
  const u16* PK3 = wsp + 294912;
  const float* BIAS = (const float*)(wsp + 368640);
  const float* B1 = BIAS;
  const float* B2 = BIAS + 256;
  const float* B3 = BIAS + 1024;
  const float* BS = BIAS + 1280;

  const int tid = threadIdx.x;
  const int wave = tid >> 6;     // 0..15
  const int lane = tid & 63;
  const int nidx = lane & 15;
  const int q = lane >> 4;
  const int b0 = blockIdx.x << 4;

  // zero tile 8 (pad/state region)
  if (tid < 512) { ACT1[4096 + tid] = 0; ACT2[4096 + tid] = 0; }
  for (int i = tid; i < 2048; i += 1024) HWs[i] = wsp[371216 + i];
  // c0 -> ACT1 (fragment order)
  for (int i = tid; i < 4096; i += 1024) {
    int b = i >> 8, k = i & 255;
    int off = ((k >> 5) << 9) + (((k >> 3) & 3) << 7) + (b << 3) + (k & 7);
    ACT1[off] = f2bf(c0[((size_t)(b0 + b) << 8) + k]);
  }
  float s0v = 0.f, s1v = 0.f, s2v = 0.f, s3v = 0.f;
  float P[16];
#pragma unroll
  for (int i = 0; i < 16; ++i) P[i] = 0.f;
  if (tid < 16) {
    float4 tg = *(const float4*)(target + ((size_t)(b0 + tid) << 9));
    s0v = tg.x; s1v = tg.y; s2v = tg.z; s3v = tg.w;
    P[0] = P[5] = P[10] = P[15] = 1.f;
    const float i60 = 1.0f / 60.0f;
    uint2 snp; snp.x = pack2(s0v * i60, s1v * i60); snp.y = pack2(s2v * i60, s3v * i60);
    *(uint2*)(ACT1 + 4096 + tid * 8) = snp;   // sn: k 256-259 -> tile8, quad0, b*8
    *(uint2*)(ACT2 + 4096 + tid * 8) = snp;
  }
  __syncthreads();

  // head assignment: 128 (o,b) pairs x 4 partial lanes (waves 0-7)
  const int hpair = tid >> 2, hpart = tid & 3;
  const int hb = hpair & 15, ho = hpair >> 4;
  const int hbaseT = (ho < 2) ? 0 : ((ho < 6) ? 8 : 16);

  for (int t = 0; t < T_STEPS; ++t) {
    // meas_t/60 -> ACT2 k 260,261 (tile8, quad0, b*8+4)
    if (tid < 16) {
      float2 mm = *(const float2*)(x + ((size_t)(b0 + tid) << 8) + (t << 1));
      *(unsigned int*)(ACT2 + 4096 + tid * 8 + 4) = pack2(mm.x * (1.f/60.f), mm.y * (1.f/60.f));
    }
    // ---- P1: stage1 cu = tanh(Wm0 . [c, sn]); ft = wave ----
    {
      f32x4 acc = {0.f, 0.f, 0.f, 0.f};
#pragma unroll
      for (int kt = 0; kt < 9; ++kt) {
        bf16x8 bf = *(const bf16x8*)(ACT1 + (kt << 9) + (lane << 3));
        bf16x8 af = *(const bf16x8*)(PK1 + ((wave * 9 + kt) << 9) + (lane << 3));
        acc = __builtin_amdgcn_mfma_f32_16x16x32_bf16(af, bf, acc, 0, 0, 0);
      }
      const int f0 = (wave << 4) + (q << 2);
      const float4 bs = *(const float4*)(B1 + f0);
      uint2 pv;
      pv.x = pack2(tanh_fast(clampf(acc[0] + bs.x, -30.f, 30.f)),
                   tanh_fast(clampf(acc[1] + bs.y, -30.f, 30.f)));
      pv.y = pack2(tanh_fast(clampf(acc[2] + bs.z, -30.f, 30.f)),
                   tanh_fast(clampf(acc[3] + bs.w, -30.f, 30.f)));
      *(uint2*)(ACT2 + dstOff(wave, q, nidx)) = pv;
    }
    __syncthreads();
    // ---- P2: stage2 (ftiles wave, wave+16, wave+32) + stage3 partial (kt 0..7) ----
    f32x4 acc3 = {0.f, 0.f, 0.f, 0.f};
    {
      f32x4 a2[3];
#pragma unroll
      for (int i = 0; i < 3; ++i) { f32x4 z = {0.f,0.f,0.f,0.f}; a2[i] = z; }
#pragma unroll
      for (int kt = 0; kt < 8; ++kt) {
        bf16x8 bf = *(const bf16x8*)(ACT2 + (kt << 9) + (lane << 3));
#pragma unroll
        for (int i = 0; i < 3; ++i) {
          bf16x8 af = *(const bf16x8*)(PK2 + (((wave + 16 * i) * 9 + kt) << 9) + (lane << 3));
          a2[i] = __builtin_amdgcn_mfma_f32_16x16x32_bf16(af, bf, a2[i], 0, 0, 0);
        }
        bf16x8 af3 = *(const bf16x8*)(PK3 + ((wave * 9 + kt) << 9) + (lane << 3));
        acc3 = __builtin_amdgcn_mfma_f32_16x16x32_bf16(af3, bf, acc3, 0, 0, 0);
      }
      {  // kt = 8 for stage2 only (sn+meas live; stale supd x zero-weights)
        bf16x8 bf = *(const bf16x8*)(ACT2 + (8 << 9) + (lane << 3));
#pragma unroll
        for (int i = 0; i < 3; ++i) {
          bf16x8 af = *(const bf16x8*)(PK2 + (((wave + 16 * i) * 9 + 8) << 9) + (lane << 3));
          a2[i] = __builtin_amdgcn_mfma_f32_16x16x32_bf16(af, bf, a2[i], 0, 0, 0);
        }
      }
#pragma unroll
      for (int i = 0; i < 3; ++i) {
        const int ft = wave + 16 * i;
        const int f0 = (ft << 4) + (q << 2);
        const float4 bs = *(const float4*)(B2 + f0);
        uint2 pv;
        pv.x = pack2(tanh_fast(clampf(a2[i][0] + bs.x, -30.f, 30.f)),
                     tanh_fast(clampf(a2[i][1] + bs.y, -30.f, 30.f)));
        pv.y = pack2(tanh_fast(clampf(a2[i][2] + bs.z, -30.f, 30.f)),
                     tanh_fast(clampf(a2[i][3] + bs.w, -30.f, 30.f)));
        *(uint2*)(S2O + dstOff(ft, q, nidx)) = pv;
      }
    }
    __syncthreads();
    // ---- heads: d|pv|hv (waves 0-7; 4 partial lanes per (o,b)) ----
    if (tid < 512) {
      const u16* ap = S2O + ((hbaseT + (hpart << 1)) << 9) + (hb << 3);
      const u16* wp = HWs + (ho << 8) + (hpart << 6);
      float p = 0.f;
#pragma unroll
      for (int c = 0; c < 8; ++c) {  // chunk: tile c>>2, quad c&3; weights linear c*8
        bf16x8 av = *(const bf16x8*)(ap + ((c >> 2) << 9) + ((c & 3) << 7));
        bf16x8 wv = *(const bf16x8*)(wp + (c << 3));
#pragma unroll
        for (int j = 0; j < 8; ++j) p += (float)av[j] * (float)wv[j];
      }
      p += __shfl_xor(p, 1);
      p += __shfl_xor(p, 2);
      if (hpart == 0) SM[hb * 8 + ho] = clampf(p + BS[ho], -64.f, 64.f);
    }
    __syncthreads();
    // ---- Kalman update (lane b of wave 0) ----
    if (tid < 16) {
      const float* sm = SM + tid * 8;
      float d0 = sm[0], d1 = sm[1];
      float pv[4] = { sm[2], sm[3], sm[4], sm[5] };
      float hv0 = sm[6], hv1 = sm[7];
      float2 mm = *(const float2*)(x + ((size_t)(b0 + tid) << 8) + (t << 1));
      float m0 = mm.x, m1 = mm.y;
      float sp[4];
      sp[0] = s0v + s2v + 0.5f * d0;
      sp[1] = s1v + s3v + 0.5f * d1;
      sp[2] = s2v + d0;
      sp[3] = s3v + d1;
      float FP[16], Pp[16];
#pragma unroll
      for (int j = 0; j < 4; ++j) {
        FP[0 * 4 + j] = P[0 * 4 + j] + P[2 * 4 + j];
        FP[1 * 4 + j] = P[1 * 4 + j] + P[3 * 4 + j];
        FP[2 * 4 + j] = P[2 * 4 + j];
        FP[3 * 4 + j] = P[3 * 4 + j];
      }
#pragma unroll
      for (int i = 0; i < 4; ++i) {
        Pp[i * 4 + 0] = FP[i * 4 + 0] + FP[i * 4 + 2];
        Pp[i * 4 + 1] = FP[i * 4 + 1] + FP[i * 4 + 3];
        Pp[i * 4 + 2] = FP[i * 4 + 2];
        Pp[i * 4 + 3] = FP[i * 4 + 3];
      }
#pragma unroll
      for (int i = 0; i < 4; ++i)
#pragma unroll
        for (int j = 0; j < 4; ++j) Pp[i * 4 + j] += pv[i] * pv[j];
#pragma unroll
      for (int i = 0; i < 4; ++i) Pp[i * 4 + i] += 0.01f;
      float in0 = m0 - sp[0], in1 = m1 - sp[1];
      float S00 = Pp[0] + hv0 * hv0 + 1.0f;
      float S01 = Pp[1] + hv0 * hv1;
      float S10 = Pp[4] + hv1 * hv0;
      float S11 = Pp[5] + hv1 * hv1 + 1.0f;
      float det = S00 * S11 - S01 * S10;
      if (!(fabsf(det) > 1e-8f)) det = 1e-8f;
      float idet = 1.0f / det;
      float i00 =  S11 * idet, i01 = -S01 * idet, i10 = -S10 * idet, i11 = S00 * idet;
      float K[8], KS[8], su[4];
#pragma unroll
      for (int i = 0; i < 4; ++i) {
        K[i * 2 + 0] = Pp[i * 4 + 0] * i00 + Pp[i * 4 + 1] * i10;
        K[i * 2 + 1] = Pp[i * 4 + 0] * i01 + Pp[i * 4 + 1] * i11;
      }
#pragma unroll
      for (int i = 0; i < 4; ++i)
        su[i] = clampf(sp[i] + K[i * 2 + 0] * in0 + K[i * 2 + 1] * in1, -131072.f, 131072.f);
#pragma unroll
      for (int i = 0; i < 4; ++i) {
        KS[i * 2 + 0] = K[i * 2 + 0] * S00 + K[i * 2 + 1] * S10;
        KS[i * 2 + 1] = K[i * 2 + 0] * S01 + K[i * 2 + 1] * S11;
      }
#pragma unroll
      for (int i = 0; i < 4; ++i)
#pragma unroll
        for (int j = 0; j < 4; ++j)
          P[i * 4 + j] = clampf(
              Pp[i * 4 + j] - (KS[i * 2 + 0] * K[j * 2 + 0] + KS[i * 2 + 1] * K[j * 2 + 1]),
              -131072.f, 131072.f);
      s0v = su[0]; s1v = su[1]; s2v = su[2]; s3v = su[3];
      float4 ov; ov.x = su[0]; ov.y = su[1]; ov.z = su[2]; ov.w = su[3];
      *(float4*)(out + ((size_t)(b0 + tid) << 9) + (t << 2)) = ov;
      const float i60 = 1.0f / 60.0f;
      uint2 snp; snp.x = pack2(su[0] * i60, su[1] * i60); snp.y = pack2(su[2] * i60, su[3] * i60);
      *(uint2*)(ACT1 + 4096 + tid * 8) = snp;          // sn_{t+1}: k 256-259
      *(uint2*)(ACT2 + 4096 + tid * 8) = snp;          // sn_{t+1}
      *(uint2*)(ACT2 + 4096 + 128 + tid * 8) = snp;    // supd/60: k 264-267 (tile8 quad1)
    }
    __syncthreads();
    // ---- P5: stage3 final (kt=8: meas+supd rows) + epilogue -> ACT1 c ----
    {
      bf16x8 bf = *(const bf16x8*)(ACT2 + (8 << 9) + (lane << 3));
      bf16x8 af = *(const bf16x8*)(PK3 + ((wave * 9 + 8) << 9) + (lane << 3));
      acc3 = __builtin_amdgcn_mfma_f32_16x16x32_bf16(af, bf, acc3, 0, 0, 0);
      const int f0 = (wave << 4) + (q << 2);
      const float4 bs = *(const float4*)(B3 + f0);
      uint2 pv;
      pv.x = pack2(tanh_fast(clampf(acc3[0] + bs.x, -30.f, 30.f)),
                   tanh_fast(clampf(acc3[1] + bs.y, -30.f, 30.f)));
      pv.y = pack2(tanh_fast(clampf(acc3[2] + bs.z, -30.f, 30.f)),
                   tanh_fast(clampf(acc3[3] + bs.w, -30.f, 30.f)));
      *(uint2*)(ACT1 + dstOff(wave, q, nidx)) = pv;
    }
    __syncthreads();
  }
}

extern "C" void kernel_launch(void* const* d_in, const int* in_sizes, int n_in,
                              void* d_out, int out_size, void* d_ws, size_t ws_size,
                              hipStream_t stream) {
  const float* x    = (const float*)d_in[0];
  const float* tgt  = (const float*)d_in[1];
  const float* c0   = (const float*)d_in[2];
  const float* Wm0  = (const float*)d_in[3];
  const float* bm0  = (const float*)d_in[4];
  const float* Wm1  = (const float*)d_in[5];
  const float* bm1  = (const float*)d_in[6];
  const float* Wf10 = (const float*)d_in[7];
  const float* bf10 = (const float*)d_in[8];
  const float* Wf11 = (const float*)d_in[9];
  const float* bf11 = (const float*)d_in[10];
  const float* Wf20 = (const float*)d_in[11];
  const float* bf20 = (const float*)d_in[12];
  const float* Wf21 = (const float*)d_in[13];
  const float* bf21 = (const float*)d_in[14];
  const float* Wh0  = (const float*)d_in[15];
  const float* bh0  = (const float*)d_in[16];
  const float* Wh1  = (const float*)d_in[17];
  const float* bh1  = (const float*)d_in[18];
  u16* ws    = (u16*)d_ws;
  float* out = (float*)d_out;

  egbrnn_prep<<<dim3(1454), dim3(256), 0, stream>>>(
      Wm0, Wm1, Wf10, Wf11, Wf20, Wf21, Wh0, Wh1,
      bm0, bm1, bf10, bf11, bf20, bf21, bh0, bh1, ws);
  egbrnn_main<<<dim3(128), dim3(1024), 0, stream>>>(x, tgt, c0, ws, out);
}

// Round 7
// 1682.282 us; speedup vs baseline: 1.6971x; 1.6971x over previous
//
#include <hip/hip_runtime.h>

typedef unsigned short u16;
typedef __bf16 bf16x8 __attribute__((ext_vector_type(8)));
typedef float  f32x4  __attribute__((ext_vector_type(4)));

#define T_STEPS 128
#define KSTR    296   // ACT row stride (u16 elems): 288 logical + pad
#define S2STR   792   // stage2 output row stride

// ---- ws element-offset layout (u16 elements unless noted) ----
// PK1  @      0 : 16 ftiles * 9 kt * 512 = 73728   (Wm0 -> bf16 A-frags)
// PK2  @  73728 : 48 * 9 * 512          = 221184   (Wf10|Wf20|Wh0)
// PK3  @ 294912 : 16 * 9 * 512          = 73728    (Wm1, rows permuted to ACT2 layout)
// BIAS @ 368640 : 1288 floats = 2576 u16 (B1[256] B2[768] B3[256] BS[8])
// HW   @ 371216 : 8 * 256 = 2048        (head weights [o][k], bf16)

__device__ __forceinline__ float bf2f(u16 h) {
  union { unsigned int u; float f; } v; v.u = ((unsigned int)h) << 16; return v.f;
}
__device__ __forceinline__ u16 f2bf(float f) {
  union { float f; unsigned int u; } v; v.f = f;
  unsigned int u = v.u;
  return (u16)((u + 0x7fffu + ((u >> 16) & 1u)) >> 16);
}
__device__ __forceinline__ unsigned int pack2(float a, float b) {
  return (unsigned int)f2bf(a) | ((unsigned int)f2bf(b) << 16);
}
__device__ __forceinline__ float clampf(float x, float lo, float hi) {
  return fmaxf(lo, fminf(x, hi));   // NaN-absorbing insurance; no-op for correct values
}
__device__ __forceinline__ float tanh_fast(float x) {
  float e = __expf(2.0f * x);
  return 1.0f - 2.0f * __builtin_amdgcn_rcpf(e + 1.0f);
}

// ---------------- weight repack: f32 -> bf16 MFMA A-fragments (runs every call) ----------------
__global__ void egbrnn_prep(
    const float* __restrict__ Wm0, const float* __restrict__ Wm1,
    const float* __restrict__ Wf10, const float* __restrict__ Wf11,
    const float* __restrict__ Wf20, const float* __restrict__ Wf21,
    const float* __restrict__ Wh0, const float* __restrict__ Wh1,
    const float* __restrict__ bm0, const float* __restrict__ bm1,
    const float* __restrict__ bf10, const float* __restrict__ bf11,
    const float* __restrict__ bf20, const float* __restrict__ bf21,
    const float* __restrict__ bh0, const float* __restrict__ bh1,
    u16* __restrict__ ws)
{
  int idx = blockIdx.x * 256 + threadIdx.x;
  // ---- PK1: Wm0, K rows: [c 0-255, sn 256-259], pad->288 ----
  if (idx < 73728) {
    int tile = idx >> 9, r = idx & 511;
    int lane = r >> 3, j = r & 7;
    int ft = tile / 9, kt = tile - ft * 9;
    int m = (ft << 4) + (lane & 15);
    int k = (kt << 5) + ((lane >> 4) << 3) + j;
    ws[idx] = (k < 260) ? f2bf(Wm0[k * 256 + m]) : (u16)0;
    return;
  }
  idx -= 73728;
  // ---- PK2: [Wf10 | Wf20 | Wh0], ACT2 K layout [cu 0-255, sn 256-259, meas/60 260-261, pad] ----
  if (idx < 221184) {
    int tile = idx >> 9, r = idx & 511;
    int lane = r >> 3, j = r & 7;
    int ft = tile / 9, kt = tile - ft * 9;
    int F = (ft << 4) + (lane & 15);
    int k = (kt << 5) + ((lane >> 4) << 3) + j;
    int sel = F >> 8, col = F & 255;
    u16 v = 0;
    if (sel == 0)      { if (k < 260) v = f2bf(Wf10[k * 256 + col]); }
    else if (sel == 1) { if (k < 260) v = f2bf(Wf20[k * 256 + col]); }
    else               { if (k < 262) v = f2bf(Wh0 [k * 256 + col]); }
    ws[73728 + idx] = v;
    return;
  }
  idx -= 221184;
  // ---- PK3: Wm1 rows permuted to ACT2 layout: k<256->cu; k 260,261->meas rows 256,257; k 264..267->supd rows 258..261 ----
  if (idx < 73728) {
    int tile = idx >> 9, r = idx & 511;
    int lane = r >> 3, j = r & 7;
    int ft = tile / 9, kt = tile - ft * 9;
    int m = (ft << 4) + (lane & 15);
    int k = (kt << 5) + ((lane >> 4) << 3) + j;
    int row = -1;
    if (k < 256) row = k;
    else if (k == 260 || k == 261) row = 256 + (k - 260);
    else if (k >= 264 && k < 268)  row = 258 + (k - 264);
    ws[294912 + idx] = (row >= 0) ? f2bf(Wm1[row * 256 + m]) : (u16)0;
    return;
  }
  idx -= 73728;
  // ---- biases (fp32) ----
  if (idx < 1288) {
    float* BIAS = (float*)(ws + 368640);
    float h;
    if (idx < 256) h = bm0[idx];
    else if (idx < 1024) {
      int f = idx - 256;
      h = (f < 256) ? bf10[f] : (f < 512 ? bf20[f - 256] : bh0[f - 512]);
    } else if (idx < 1280) h = bm1[idx - 1024];
    else {
      int i2 = idx - 1280;
      h = (i2 < 2) ? bf11[i2] : (i2 < 6 ? bf21[i2 - 2] : bh1[i2 - 6]);
    }
    BIAS[idx] = h;
    return;
  }
  idx -= 1288;
  // ---- head weights [o][k], bf16 ----
  if (idx < 2048) {
    int o = idx >> 8, k = idx & 255;
    float v;
    if (o < 2)      v = Wf11[k * 2 + o];
    else if (o < 6) v = Wf21[k * 4 + (o - 2)];
    else            v = Wh1[k * 2 + (o - 6)];
    ws[371216 + idx] = f2bf(v);
  }
}

// ---------------- one MFMA stage: out[f][b] = tanh(sum_k W[k][f]*actIn[b][k] + bias[f]) ----------------
template<int NFT, int NKT>
__device__ __forceinline__ void stage_mm(
    const u16* __restrict__ pk, const float* __restrict__ bias,
    const u16* __restrict__ actIn, int inStride,
    u16* __restrict__ actOut, int outStride,
    int ft0, int ftStep, int lane)
{
  const int nidx = lane & 15;
  const int q = lane >> 4;
  f32x4 acc[NFT];
#pragma unroll
  for (int i = 0; i < NFT; ++i) { f32x4 z = {0.f, 0.f, 0.f, 0.f}; acc[i] = z; }
  const u16* bbase = actIn + nidx * inStride + (q << 3);
#pragma unroll 3
  for (int kt = 0; kt < NKT; ++kt) {
    bf16x8 bf = *(const bf16x8*)(bbase + (kt << 5));
#pragma unroll
    for (int i = 0; i < NFT; ++i) {
      const int ft = ft0 + i * ftStep;
      bf16x8 af = *(const bf16x8*)(pk + (((ft * NKT) + kt) << 9) + (lane << 3));
      acc[i] = __builtin_amdgcn_mfma_f32_16x16x32_bf16(af, bf, acc[i], 0, 0, 0);
    }
  }
#pragma unroll
  for (int i = 0; i < NFT; ++i) {
    const int ft = ft0 + i * ftStep;
    const int f0 = (ft << 4) + (q << 2);
    const float4 bs = *(const float4*)(bias + f0);
    float v0 = tanh_fast(clampf(acc[i][0] + bs.x, -30.f, 30.f));
    float v1 = tanh_fast(clampf(acc[i][1] + bs.y, -30.f, 30.f));
    float v2 = tanh_fast(clampf(acc[i][2] + bs.z, -30.f, 30.f));
    float v3 = tanh_fast(clampf(acc[i][3] + bs.w, -30.f, 30.f));
    uint2 pv; pv.x = pack2(v0, v1); pv.y = pack2(v2, v3);
    *(uint2*)(actOut + nidx * outStride + f0) = pv;
  }
}

// ---------------- main: 256 blocks x 512 threads (8 waves), 8 batch rows per block ----------------
// Per-block work is weight-dominated (720 KB/step regardless of rows), so halving rows/block
// to fill all 256 CUs costs ~nothing per block. MFMA N-dim half-used (MFMA is ~5% busy).
__global__ __launch_bounds__(512, 1) void egbrnn_main(
    const float* __restrict__ x, const float* __restrict__ target,
    const float* __restrict__ c0, const u16* __restrict__ wsp,
    float* __restrict__ out)
{
  __shared__ __align__(16) u16 ACT1[16 * KSTR];  // [b][k]: 0-255 c, 256-259 sn, pad (rows 8-15 zero)
  __shared__ __align__(16) u16 ACT2[16 * KSTR];  // [b][k]: cu, sn, meas/60, supd/60
  __shared__ __align__(16) u16 S2O [16 * S2STR]; // [b][f]: t1 | t2 | th
  __shared__ __align__(16) u16 HWs [8 * 256];    // head weights [o][k]
  __shared__ __align__(16) float SM[16 * 8];     // [b][o]: d0 d1 pv0..3 hv0 hv1

  const u16* PK1 = wsp;
  const u16* PK2 = wsp + 73728;
  const u16* PK3 = wsp + 294912;
  const float* BIAS = (const float*)(wsp + 368640);
  const float* B1 = BIAS;
  const float* B2 = BIAS + 256;
  const float* B3 = BIAS + 1024;
  const float* BS = BIAS + 1280;

  const int tid = threadIdx.x;
  const int wave = tid >> 6;
  const int lane = tid & 63;
  const int b0 = blockIdx.x << 3;   // 8 batch rows per block

  // zero pad cols 256..295 of ACT1/ACT2 (all 16 rows)
  for (int i = tid; i < 16 * (KSTR - 256); i += 512) {
    int b = i / (KSTR - 256), k = 256 + (i - b * (KSTR - 256));
    ACT1[b * KSTR + k] = 0; ACT2[b * KSTR + k] = 0;
  }
  // head weights -> LDS
  for (int i = tid; i < 2048; i += 512) HWs[i] = wsp[371216 + i];
  // c0 -> ACT1 rows 0-7; rows 8-15 zero (keeps unused N columns finite)
  for (int i = tid; i < 16 * 256; i += 512) {
    int b = i >> 8, k = i & 255;
    ACT1[b * KSTR + k] = (b < 8) ? f2bf(c0[((size_t)(b0 + b) << 8) + k]) : (u16)0;
  }
  float s0v = 0.f, s1v = 0.f, s2v = 0.f, s3v = 0.f;
  float P[16];
#pragma unroll
  for (int i = 0; i < 16; ++i) P[i] = 0.f;
  if (tid < 8) {
    float4 tg = *(const float4*)(target + ((size_t)(b0 + tid) << 9));
    s0v = tg.x; s1v = tg.y; s2v = tg.z; s3v = tg.w;
    P[0] = P[5] = P[10] = P[15] = 1.f;
    const float i60 = 1.0f / 60.0f;
    uint2 snp; snp.x = pack2(s0v * i60, s1v * i60); snp.y = pack2(s2v * i60, s3v * i60);
    *(uint2*)(ACT1 + tid * KSTR + 256) = snp;
    *(uint2*)(ACT2 + tid * KSTR + 256) = snp;
  }
  __syncthreads();

  // head assignment: (o,b) pairs x 4 partial lanes; only hb<8 results consumed
  const int hpair = tid >> 2, hpart = tid & 3;
  const int hb = hpair & 15, ho = hpair >> 4;
  const int hcolBase = (ho < 2) ? 0 : ((ho < 6) ? 256 : 512);

  for (int t = 0; t < T_STEPS; ++t) {
    // meas_t/60 -> ACT2[260..261] rows 0-7
    if (tid < 8) {
      float2 mm = *(const float2*)(x + ((size_t)(b0 + tid) << 8) + (t << 1));
      *(unsigned int*)(ACT2 + tid * KSTR + 260) = pack2(mm.x * (1.f / 60.f), mm.y * (1.f / 60.f));
    }
    // stage1: cu = tanh(Wm0 . [c, sn])
    stage_mm<2, 9>(PK1, B1, ACT1, KSTR, ACT2, KSTR, wave, 8, lane);
    __syncthreads();
    // stage2: t1|t2|th = tanh([Wf10|Wf20|Wh0] . [cu, sn, meas/60])
    stage_mm<6, 9>(PK2, B2, ACT2, KSTR, S2O, S2STR, wave, 8, lane);
    __syncthreads();
    // small heads: (o,b) dots of length 256; 4 partial lanes each
    {
      const u16* ap = S2O + hb * S2STR + hcolBase + (hpart << 6);
      const u16* wp = HWs + (ho << 8) + (hpart << 6);
      float p = 0.f;
#pragma unroll
      for (int i = 0; i < 8; ++i) {
        bf16x8 av = *(const bf16x8*)(ap + (i << 3));
        bf16x8 wv = *(const bf16x8*)(wp + (i << 3));
#pragma unroll
        for (int j = 0; j < 8; ++j) p += (float)av[j] * (float)wv[j];
      }
      p += __shfl_xor(p, 1);
      p += __shfl_xor(p, 2);
      if (hpart == 0) SM[hb * 8 + ho] = clampf(p + BS[ho], -64.f, 64.f);
    }
    __syncthreads();
    // Kalman update (lane b owns batch row b; s,P fp32 registers)
    if (tid < 8) {
      const float* sm = SM + tid * 8;
      float d0 = sm[0], d1 = sm[1];
      float pv[4] = { sm[2], sm[3], sm[4], sm[5] };
      float hv0 = sm[6], hv1 = sm[7];
      float2 mm = *(const float2*)(x + ((size_t)(b0 + tid) << 8) + (t << 1));
      float m0 = mm.x, m1 = mm.y;
      float sp[4];
      sp[0] = s0v + s2v + 0.5f * d0;
      sp[1] = s1v + s3v + 0.5f * d1;
      sp[2] = s2v + d0;
      sp[3] = s3v + d1;
      float FP[16], Pp[16];
#pragma unroll
      for (int j = 0; j < 4; ++j) {
        FP[0 * 4 + j] = P[0 * 4 + j] + P[2 * 4 + j];
        FP[1 * 4 + j] = P[1 * 4 + j] + P[3 * 4 + j];
        FP[2 * 4 + j] = P[2 * 4 + j];
        FP[3 * 4 + j] = P[3 * 4 + j];
      }
#pragma unroll
      for (int i = 0; i < 4; ++i) {
        Pp[i * 4 + 0] = FP[i * 4 + 0] + FP[i * 4 + 2];
        Pp[i * 4 + 1] = FP[i * 4 + 1] + FP[i * 4 + 3];
        Pp[i * 4 + 2] = FP[i * 4 + 2];
        Pp[i * 4 + 3] = FP[i * 4 + 3];
      }
#pragma unroll
      for (int i = 0; i < 4; ++i)
#pragma unroll
        for (int j = 0; j < 4; ++j) Pp[i * 4 + j] += pv[i] * pv[j];
#pragma unroll
      for (int i = 0; i < 4; ++i) Pp[i * 4 + i] += 0.01f;
      float in0 = m0 - sp[0], in1 = m1 - sp[1];
      float S00 = Pp[0] + hv0 * hv0 + 1.0f;
      float S01 = Pp[1] + hv0 * hv1;
      float S10 = Pp[4] + hv1 * hv0;
      float S11 = Pp[5] + hv1 * hv1 + 1.0f;
      float det = S00 * S11 - S01 * S10;
      if (!(fabsf(det) > 1e-8f)) det = 1e-8f;
      float idet = 1.0f / det;
      float i00 =  S11 * idet, i01 = -S01 * idet, i10 = -S10 * idet, i11 = S00 * idet;
      float K[8], KS[8], su[4];
#pragma unroll
      for (int i = 0; i < 4; ++i) {
        K[i * 2 + 0] = Pp[i * 4 + 0] * i00 + Pp[i * 4 + 1] * i10;
        K[i * 2 + 1] = Pp[i * 4 + 0] * i01 + Pp[i * 4 + 1] * i11;
      }
#pragma unroll
      for (int i = 0; i < 4; ++i)
        su[i] = clampf(sp[i] + K[i * 2 + 0] * in0 + K[i * 2 + 1] * in1, -131072.f, 131072.f);
#pragma unroll
      for (int i = 0; i < 4; ++i) {
        KS[i * 2 + 0] = K[i * 2 + 0] * S00 + K[i * 2 + 1] * S10;
        KS[i * 2 + 1] = K[i * 2 + 0] * S01 + K[i * 2 + 1] * S11;
      }
#pragma unroll
      for (int i = 0; i < 4; ++i)
#pragma unroll
        for (int j = 0; j < 4; ++j)
          P[i * 4 + j] = clampf(
              Pp[i * 4 + j] - (KS[i * 2 + 0] * K[j * 2 + 0] + KS[i * 2 + 1] * K[j * 2 + 1]),
              -131072.f, 131072.f);
      s0v = su[0]; s1v = su[1]; s2v = su[2]; s3v = su[3];
      // emit output s_upd (f32)
      float4 ov; ov.x = su[0]; ov.y = su[1]; ov.z = su[2]; ov.w = su[3];
      *(float4*)(out + ((size_t)(b0 + tid) << 9) + (t << 2)) = ov;
      // next-step sn and this-step supd/60 (bf16)
      const float i60 = 1.0f / 60.0f;
      uint2 snp; snp.x = pack2(su[0] * i60, su[1] * i60); snp.y = pack2(su[2] * i60, su[3] * i60);
      *(uint2*)(ACT1 + tid * KSTR + 256) = snp;
      *(uint2*)(ACT2 + tid * KSTR + 256) = snp;
      *(uint2*)(ACT2 + tid * KSTR + 264) = snp;
    }
    __syncthreads();
    // stage3: c_new = tanh(Wm1 . [cu, meas/60, supd/60]) -> ACT1[:,0:256]
    stage_mm<2, 9>(PK3, B3, ACT2, KSTR, ACT1, KSTR, wave, 8, lane);
    __syncthreads();
  }
}

extern "C" void kernel_launch(void* const* d_in, const int* in_sizes, int n_in,
                              void* d_out, int out_size, void* d_ws, size_t ws_size,
                              hipStream_t stream) {
  const float* x    = (const float*)d_in[0];
  const float* tgt  = (const float*)d_in[1];
  const float* c0   = (const float*)d_in[2];
  const float* Wm0  = (const float*)d_in[3];
  const float* bm0  = (const float*)d_in[4];
  const float* Wm1  = (const float*)d_in[5];
  const float* bm1  = (const float*)d_in[6];
  const float* Wf10 = (const float*)d_in[7];
  const float* bf10 = (const float*)d_in[8];
  const float* Wf11 = (const float*)d_in[9];
  const float* bf11 = (const float*)d_in[10];
  const float* Wf20 = (const float*)d_in[11];
  const float* bf20 = (const float*)d_in[12];
  const float* Wf21 = (const float*)d_in[13];
  const float* bf21 = (const float*)d_in[14];
  const float* Wh0  = (const float*)d_in[15];
  const float* bh0  = (const float*)d_in[16];
  const float* Wh1  = (const float*)d_in[17];
  const float* bh1  = (const float*)d_in[18];
  u16* ws    = (u16*)d_ws;
  float* out = (float*)d_out;

  egbrnn_prep<<<dim3(1454), dim3(256), 0, stream>>>(
      Wm0, Wm1, Wf10, Wf11, Wf20, Wf21, Wh0, Wh1,
      bm0, bm1, bf10, bf11, bf20, bf21, bh0, bh1, ws);
  egbrnn_main<<<dim3(256), dim3(512), 0, stream>>>(x, tgt, c0, ws, out);
}

// Round 8
// 1134.027 us; speedup vs baseline: 2.5176x; 1.4835x over previous
//
#include <hip/hip_runtime.h>

typedef unsigned short u16;
typedef __bf16 bf16x8 __attribute__((ext_vector_type(8)));
typedef float  f32x4  __attribute__((ext_vector_type(4)));

#define T_STEPS 128
#define KSTR    296   // ACT row stride (u16 elems): 288 logical + pad
#define S2STR   792   // stage2 output row stride

// ---- ws element-offset layout (u16 elements unless noted) ----
// PK1  @      0 : 16 ftiles * 9 kt * 512 = 73728   (Wm0 -> bf16 A-frags)
// PK2  @  73728 : 48 * 9 * 512          = 221184   (Wf10|Wf20|Wh0)
// PK3  @ 294912 : 16 * 9 * 512          = 73728    (Wm1, rows permuted to ACT2 layout)
// BIAS @ 368640 : 1288 floats = 2576 u16 (B1[256] B2[768] B3[256] BS[8])
// HW   @ 371216 : 8 * 256 = 2048        (head weights [o][k], bf16)

__device__ __forceinline__ float bf2f(u16 h) {
  union { unsigned int u; float f; } v; v.u = ((unsigned int)h) << 16; return v.f;
}
__device__ __forceinline__ u16 f2bf(float f) {
  union { float f; unsigned int u; } v; v.f = f;
  unsigned int u = v.u;
  return (u16)((u + 0x7fffu + ((u >> 16) & 1u)) >> 16);
}
__device__ __forceinline__ unsigned int pack2(float a, float b) {
  return (unsigned int)f2bf(a) | ((unsigned int)f2bf(b) << 16);
}
__device__ __forceinline__ float clampf(float x, float lo, float hi) {
  return fmaxf(lo, fminf(x, hi));   // NaN-absorbing insurance; no-op for correct values
}
__device__ __forceinline__ float tanh_fast(float x) {
  float e = __expf(2.0f * x);
  return 1.0f - 2.0f * __builtin_amdgcn_rcpf(e + 1.0f);
}

// ---------------- weight repack: f32 -> bf16 MFMA A-fragments (runs every call) ----------------
__global__ void egbrnn_prep(
    const float* __restrict__ Wm0, const float* __restrict__ Wm1,
    const float* __restrict__ Wf10, const float* __restrict__ Wf11,
    const float* __restrict__ Wf20, const float* __restrict__ Wf21,
    const float* __restrict__ Wh0, const float* __restrict__ Wh1,
    const float* __restrict__ bm0, const float* __restrict__ bm1,
    const float* __restrict__ bf10, const float* __restrict__ bf11,
    const float* __restrict__ bf20, const float* __restrict__ bf21,
    const float* __restrict__ bh0, const float* __restrict__ bh1,
    u16* __restrict__ ws)
{
  int idx = blockIdx.x * 256 + threadIdx.x;
  // ---- PK1: Wm0, K rows: [c 0-255, sn 256-259], pad->288 ----
  if (idx < 73728) {
    int tile = idx >> 9, r = idx & 511;
    int lane = r >> 3, j = r & 7;
    int ft = tile / 9, kt = tile - ft * 9;
    int m = (ft << 4) + (lane & 15);
    int k = (kt << 5) + ((lane >> 4) << 3) + j;
    ws[idx] = (k < 260) ? f2bf(Wm0[k * 256 + m]) : (u16)0;
    return;
  }
  idx -= 73728;
  // ---- PK2: [Wf10 | Wf20 | Wh0], ACT2 K layout [cu 0-255, sn 256-259, meas/60 260-261, pad] ----
  if (idx < 221184) {
    int tile = idx >> 9, r = idx & 511;
    int lane = r >> 3, j = r & 7;
    int ft = tile / 9, kt = tile - ft * 9;
    int F = (ft << 4) + (lane & 15);
    int k = (kt << 5) + ((lane >> 4) << 3) + j;
    int sel = F >> 8, col = F & 255;
    u16 v = 0;
    if (sel == 0)      { if (k < 260) v = f2bf(Wf10[k * 256 + col]); }
    else if (sel == 1) { if (k < 260) v = f2bf(Wf20[k * 256 + col]); }
    else               { if (k < 262) v = f2bf(Wh0 [k * 256 + col]); }
    ws[73728 + idx] = v;
    return;
  }
  idx -= 221184;
  // ---- PK3: Wm1 rows permuted to ACT2 layout: k<256->cu; k 260,261->meas rows 256,257; k 264..267->supd rows 258..261 ----
  if (idx < 73728) {
    int tile = idx >> 9, r = idx & 511;
    int lane = r >> 3, j = r & 7;
    int ft = tile / 9, kt = tile - ft * 9;
    int m = (ft << 4) + (lane & 15);
    int k = (kt << 5) + ((lane >> 4) << 3) + j;
    int row = -1;
    if (k < 256) row = k;
    else if (k == 260 || k == 261) row = 256 + (k - 260);
    else if (k >= 264 && k < 268)  row = 258 + (k - 264);
    ws[294912 + idx] = (row >= 0) ? f2bf(Wm1[row * 256 + m]) : (u16)0;
    return;
  }
  idx -= 73728;
  // ---- biases (fp32) ----
  if (idx < 1288) {
    float* BIAS = (float*)(ws + 368640);
    float h;
    if (idx < 256) h = bm0[idx];
    else if (idx < 1024) {
      int f = idx - 256;
      h = (f < 256) ? bf10[f] : (f < 512 ? bf20[f - 256] : bh0[f - 512]);
    } else if (idx < 1280) h = bm1[idx - 1024];
    else {
      int i2 = idx - 1280;
      h = (i2 < 2) ? bf11[i2] : (i2 < 6 ? bf21[i2 - 2] : bh1[i2 - 6]);
    }
    BIAS[idx] = h;
    return;
  }
  idx -= 1288;
  // ---- head weights [o][k], bf16 ----
  if (idx < 2048) {
    int o = idx >> 8, k = idx & 255;
    float v;
    if (o < 2)      v = Wf11[k * 2 + o];
    else if (o < 6) v = Wf21[k * 4 + (o - 2)];
    else            v = Wh1[k * 2 + (o - 6)];
    ws[371216 + idx] = f2bf(v);
  }
}

// ---------------- one MFMA stage: out[f][b] = tanh(sum_k W[k][f]*actIn[b][k] + bias[f]) ----------------
template<int NFT, int NKT>
__device__ __forceinline__ void stage_mm(
    const u16* __restrict__ pk, const float* __restrict__ bias,
    const u16* __restrict__ actIn, int inStride,
    u16* __restrict__ actOut, int outStride,
    int ft0, int ftStep, int lane)
{
  const int nidx = lane & 15;
  const int q = lane >> 4;
  f32x4 acc[NFT];
#pragma unroll
  for (int i = 0; i < NFT; ++i) { f32x4 z = {0.f, 0.f, 0.f, 0.f}; acc[i] = z; }
  const u16* bbase = actIn + nidx * inStride + (q << 3);
#pragma unroll 3
  for (int kt = 0; kt < NKT; ++kt) {
    bf16x8 bf = *(const bf16x8*)(bbase + (kt << 5));
#pragma unroll
    for (int i = 0; i < NFT; ++i) {
      const int ft = ft0 + i * ftStep;
      bf16x8 af = *(const bf16x8*)(pk + (((ft * NKT) + kt) << 9) + (lane << 3));
      acc[i] = __builtin_amdgcn_mfma_f32_16x16x32_bf16(af, bf, acc[i], 0, 0, 0);
    }
  }
#pragma unroll
  for (int i = 0; i < NFT; ++i) {
    const int ft = ft0 + i * ftStep;
    const int f0 = (ft << 4) + (q << 2);
    const float4 bs = *(const float4*)(bias + f0);
    float v0 = tanh_fast(clampf(acc[i][0] + bs.x, -30.f, 30.f));
    float v1 = tanh_fast(clampf(acc[i][1] + bs.y, -30.f, 30.f));
    float v2 = tanh_fast(clampf(acc[i][2] + bs.z, -30.f, 30.f));
    float v3 = tanh_fast(clampf(acc[i][3] + bs.w, -30.f, 30.f));
    uint2 pv; pv.x = pack2(v0, v1); pv.y = pack2(v2, v3);
    *(uint2*)(actOut + nidx * outStride + f0) = pv;
  }
}

// ---------------- main: 128 blocks x 1024 threads (16 waves, 4/SIMD), 16 batch rows per block ----------------
// R5 structure unchanged; only waves/block doubled so each wave streams half the weight
// bytes per step and the SIMD has 4 contexts to keep L2 loads in flight.
__global__ __launch_bounds__(1024, 4) void egbrnn_main(
    const float* __restrict__ x, const float* __restrict__ target,
    const float* __restrict__ c0, const u16* __restrict__ wsp,
    float* __restrict__ out)
{
  __shared__ __align__(16) u16 ACT1[16 * KSTR];  // [b][k]: 0-255 c, 256-259 sn, pad
  __shared__ __align__(16) u16 ACT2[16 * KSTR];  // [b][k]: cu, sn, meas/60, supd/60
  __shared__ __align__(16) u16 S2O [16 * S2STR]; // [b][f]: t1 | t2 | th
  __shared__ __align__(16) u16 HWs [8 * 256];    // head weights [o][k]
  __shared__ __align__(16) float SM[16 * 8];     // [b][o]: d0 d1 pv0..3 hv0 hv1

  const u16* PK1 = wsp;
  const u16* PK2 = wsp + 73728;
  const u16* PK3 = wsp + 294912;
  const float* BIAS = (const float*)(wsp + 368640);
  const float* B1 = BIAS;
  const float* B2 = BIAS + 256;
  const float* B3 = BIAS + 1024;
  const float* BS = BIAS + 1280;

  const int tid = threadIdx.x;
  const int wave = tid >> 6;     // 0..15
  const int lane = tid & 63;
  const int b0 = blockIdx.x << 4;   // 16 batch rows per block

  // zero pad cols 256..295 of ACT1/ACT2
  for (int i = tid; i < 16 * (KSTR - 256); i += 1024) {
    int b = i / (KSTR - 256), k = 256 + (i - b * (KSTR - 256));
    ACT1[b * KSTR + k] = 0; ACT2[b * KSTR + k] = 0;
  }
  // head weights -> LDS
  for (int i = tid; i < 2048; i += 1024) HWs[i] = wsp[371216 + i];
  // c0 -> ACT1
  for (int i = tid; i < 16 * 256; i += 1024) {
    int b = i >> 8, k = i & 255;
    ACT1[b * KSTR + k] = f2bf(c0[((size_t)(b0 + b) << 8) + k]);
  }
  float s0v = 0.f, s1v = 0.f, s2v = 0.f, s3v = 0.f;
  float P[16];
#pragma unroll
  for (int i = 0; i < 16; ++i) P[i] = 0.f;
  if (tid < 16) {
    float4 tg = *(const float4*)(target + ((size_t)(b0 + tid) << 9));
    s0v = tg.x; s1v = tg.y; s2v = tg.z; s3v = tg.w;
    P[0] = P[5] = P[10] = P[15] = 1.f;
    const float i60 = 1.0f / 60.0f;
    uint2 snp; snp.x = pack2(s0v * i60, s1v * i60); snp.y = pack2(s2v * i60, s3v * i60);
    *(uint2*)(ACT1 + tid * KSTR + 256) = snp;
    *(uint2*)(ACT2 + tid * KSTR + 256) = snp;
  }
  __syncthreads();

  // head assignment: 128 (o,b) pairs x 4 partial lanes (tid < 512)
  const int hpair = tid >> 2, hpart = tid & 3;
  const int hb = hpair & 15, ho = hpair >> 4;
  const int hcolBase = (ho < 2) ? 0 : ((ho < 6) ? 256 : 512);

  for (int t = 0; t < T_STEPS; ++t) {
    // meas_t/60 -> ACT2[260..261]
    if (tid < 16) {
      float2 mm = *(const float2*)(x + ((size_t)(b0 + tid) << 8) + (t << 1));
      *(unsigned int*)(ACT2 + tid * KSTR + 260) = pack2(mm.x * (1.f / 60.f), mm.y * (1.f / 60.f));
    }
    // stage1: cu = tanh(Wm0 . [c, sn]); 16 waves x 1 ftile
    stage_mm<1, 9>(PK1, B1, ACT1, KSTR, ACT2, KSTR, wave, 16, lane);
    __syncthreads();
    // stage2: t1|t2|th; 16 waves x 3 ftiles (wave, wave+16, wave+32)
    stage_mm<3, 9>(PK2, B2, ACT2, KSTR, S2O, S2STR, wave, 16, lane);
    __syncthreads();
    // small heads: 128 (o,b) dots of length 256; 4 partial lanes each
    if (tid < 512) {
      const u16* ap = S2O + hb * S2STR + hcolBase + (hpart << 6);
      const u16* wp = HWs + (ho << 8) + (hpart << 6);
      float p = 0.f;
#pragma unroll
      for (int i = 0; i < 8; ++i) {
        bf16x8 av = *(const bf16x8*)(ap + (i << 3));
        bf16x8 wv = *(const bf16x8*)(wp + (i << 3));
#pragma unroll
        for (int j = 0; j < 8; ++j) p += (float)av[j] * (float)wv[j];
      }
      p += __shfl_xor(p, 1);
      p += __shfl_xor(p, 2);
      if (hpart == 0) SM[hb * 8 + ho] = clampf(p + BS[ho], -64.f, 64.f);
    }
    __syncthreads();
    // Kalman update (lane b owns batch row b; s,P fp32 registers)
    if (tid < 16) {
      const float* sm = SM + tid * 8;
      float d0 = sm[0], d1 = sm[1];
      float pv[4] = { sm[2], sm[3], sm[4], sm[5] };
      float hv0 = sm[6], hv1 = sm[7];
      float2 mm = *(const float2*)(x + ((size_t)(b0 + tid) << 8) + (t << 1));
      float m0 = mm.x, m1 = mm.y;
      float sp[4];
      sp[0] = s0v + s2v + 0.5f * d0;
      sp[1] = s1v + s3v + 0.5f * d1;
      sp[2] = s2v + d0;
      sp[3] = s3v + d1;
      float FP[16], Pp[16];
#pragma unroll
      for (int j = 0; j < 4; ++j) {
        FP[0 * 4 + j] = P[0 * 4 + j] + P[2 * 4 + j];
        FP[1 * 4 + j] = P[1 * 4 + j] + P[3 * 4 + j];
        FP[2 * 4 + j] = P[2 * 4 + j];
        FP[3 * 4 + j] = P[3 * 4 + j];
      }
#pragma unroll
      for (int i = 0; i < 4; ++i) {
        Pp[i * 4 + 0] = FP[i * 4 + 0] + FP[i * 4 + 2];
        Pp[i * 4 + 1] = FP[i * 4 + 1] + FP[i * 4 + 3];
        Pp[i * 4 + 2] = FP[i * 4 + 2];
        Pp[i * 4 + 3] = FP[i * 4 + 3];
      }
#pragma unroll
      for (int i = 0; i < 4; ++i)
#pragma unroll
        for (int j = 0; j < 4; ++j) Pp[i * 4 + j] += pv[i] * pv[j];
#pragma unroll
      for (int i = 0; i < 4; ++i) Pp[i * 4 + i] += 0.01f;
      float in0 = m0 - sp[0], in1 = m1 - sp[1];
      float S00 = Pp[0] + hv0 * hv0 + 1.0f;
      float S01 = Pp[1] + hv0 * hv1;
      float S10 = Pp[4] + hv1 * hv0;
      float S11 = Pp[5] + hv1 * hv1 + 1.0f;
      float det = S00 * S11 - S01 * S10;
      if (!(fabsf(det) > 1e-8f)) det = 1e-8f;
      float idet = 1.0f / det;
      float i00 =  S11 * idet, i01 = -S01 * idet, i10 = -S10 * idet, i11 = S00 * idet;
      float K[8], KS[8], su[4];
#pragma unroll
      for (int i = 0; i < 4; ++i) {
        K[i * 2 + 0] = Pp[i * 4 + 0] * i00 + Pp[i * 4 + 1] * i10;
        K[i * 2 + 1] = Pp[i * 4 + 0] * i01 + Pp[i * 4 + 1] * i11;
      }
#pragma unroll
      for (int i = 0; i < 4; ++i)
        su[i] = clampf(sp[i] + K[i * 2 + 0] * in0 + K[i * 2 + 1] * in1, -131072.f, 131072.f);
#pragma unroll
      for (int i = 0; i < 4; ++i) {
        KS[i * 2 + 0] = K[i * 2 + 0] * S00 + K[i * 2 + 1] * S10;
        KS[i * 2 + 1] = K[i * 2 + 0] * S01 + K[i * 2 + 1] * S11;
      }
#pragma unroll
      for (int i = 0; i < 4; ++i)
#pragma unroll
        for (int j = 0; j < 4; ++j)
          P[i * 4 + j] = clampf(
              Pp[i * 4 + j] - (KS[i * 2 + 0] * K[j * 2 + 0] + KS[i * 2 + 1] * K[j * 2 + 1]),
              -131072.f, 131072.f);
      s0v = su[0]; s1v = su[1]; s2v = su[2]; s3v = su[3];
      // emit output s_upd (f32)
      float4 ov; ov.x = su[0]; ov.y = su[1]; ov.z = su[2]; ov.w = su[3];
      *(float4*)(out + ((size_t)(b0 + tid) << 9) + (t << 2)) = ov;
      // next-step sn and this-step supd/60 (bf16)
      const float i60 = 1.0f / 60.0f;
      uint2 snp; snp.x = pack2(su[0] * i60, su[1] * i60); snp.y = pack2(su[2] * i60, su[3] * i60);
      *(uint2*)(ACT1 + tid * KSTR + 256) = snp;
      *(uint2*)(ACT2 + tid * KSTR + 256) = snp;
      *(uint2*)(ACT2 + tid * KSTR + 264) = snp;
    }
    __syncthreads();
    // stage3: c_new = tanh(Wm1 . [cu, meas/60, supd/60]) -> ACT1[:,0:256]
    stage_mm<1, 9>(PK3, B3, ACT2, KSTR, ACT1, KSTR, wave, 16, lane);
    __syncthreads();
  }
}

extern "C" void kernel_launch(void* const* d_in, const int* in_sizes, int n_in,
                              void* d_out, int out_size, void* d_ws, size_t ws_size,
                              hipStream_t stream) {
  const float* x    = (const float*)d_in[0];
  const float* tgt  = (const float*)d_in[1];
  const float* c0   = (const float*)d_in[2];
  const float* Wm0  = (const float*)d_in[3];
  const float* bm0  = (const float*)d_in[4];
  const float* Wm1  = (const float*)d_in[5];
  const float* bm1  = (const float*)d_in[6];
  const float* Wf10 = (const float*)d_in[7];
  const float* bf10 = (const float*)d_in[8];
  const float* Wf11 = (const float*)d_in[9];
  const float* bf11 = (const float*)d_in[10];
  const float* Wf20 = (const float*)d_in[11];
  const float* bf20 = (const float*)d_in[12];
  const float* Wf21 = (const float*)d_in[13];
  const float* bf21 = (const float*)d_in[14];
  const float* Wh0  = (const float*)d_in[15];
  const float* bh0  = (const float*)d_in[16];
  const float* Wh1  = (const float*)d_in[17];
  const float* bh1  = (const float*)d_in[18];
  u16* ws    = (u16*)d_ws;
  float* out = (float*)d_out;

  egbrnn_prep<<<dim3(1454), dim3(256), 0, stream>>>(
      Wm0, Wm1, Wf10, Wf11, Wf20, Wf21, Wh0, Wh1,
      bm0, bm1, bf10, bf11, bf20, bf21, bh0, bh1, ws);
  egbrnn_main<<<dim3(128), dim3(1024), 0, stream>>>(x, tgt, c0, ws, out);
}